// Round 5
// baseline (722.215 us; speedup 1.0000x reference)
//
#include <hip/hip_runtime.h>

#define BN 8192
#define EE 262144
#define HIDD 128
#define NRBF 64
#define NBLK 4
#define TLUT 1024
#define CAP 128
#define GRID 512
#define NTHR 256
#define MR 16
#define RCUTF 6.0f
#define GAMMAF (10.0f / 36.0f)

typedef unsigned short u16;
typedef __attribute__((ext_vector_type(8))) short short8x;
typedef __attribute__((ext_vector_type(4))) float f32x4;

struct P {
    const int* Z; const float* pos; const int* ei;
    const float* ew;
    const float* ew1; const float* eb1; const float* ew2; const float* eb2;
    const float* liw; const float* nw1; const float* nb1;
    const float* nw2; const float* nb2;
    const float* lng; const float* lnb;
    const float* rw1; const float* rb1; const float* rw2; const float* rb2;
    float* out; int out_n;
    float* h; u16* xb0; u16* xb1; u16* lutall;
    u16* liwT; u16* nw1T; u16* nw2T; u16* ro1T;
    int* cnt; int2* meta; int* bar;
};

__device__ __forceinline__ float silu_f(float v) {
    return v / (1.0f + __expf(-v));
}
__device__ __forceinline__ float bf2f(u16 u) {
    return __uint_as_float(((unsigned)u) << 16);
}
__device__ __forceinline__ u16 f2bf(float f) {
    unsigned u = __float_as_uint(f);
    unsigned r = u + 0x7FFFu + ((u >> 16) & 1u);
    return (u16)(r >> 16);
}

// device-scope grid barrier; counter must be zeroed before launch.
// all blocks co-resident: 512 blocks, 52KB LDS -> 3 blocks/CU capacity.
__device__ __forceinline__ void gbar(int* b) {
    __syncthreads();
    if (threadIdx.x == 0) {
        __hip_atomic_fetch_add(b, 1, __ATOMIC_ACQ_REL, __HIP_MEMORY_SCOPE_AGENT);
        while (__hip_atomic_load(b, __ATOMIC_ACQUIRE, __HIP_MEMORY_SCOPE_AGENT) < GRID)
            __builtin_amdgcn_s_sleep(8);
    }
    __syncthreads();
}

__device__ __forceinline__ void stage_wt(u16 Wt[][136], const u16* __restrict__ src,
                                         int rows) {
    int tid = threadIdx.x;
    int chunks = rows * 16;
    for (int idx = tid; idx < chunks; idx += NTHR) {
        int r = idx >> 4, c = (idx & 15) * 8;
        *(float4*)&Wt[r][c] = *(const float4*)&src[r * HIDD + c];
    }
}

// C[16 x 32] per wave: A = 16 rows, B rows n0..n0+31 (B pre-transposed [n][k])
__device__ __forceinline__ void gemm16(const u16 A[][136], const u16 B[][136],
                                       int n0, f32x4& a0, f32x4& a1) {
    int l = threadIdx.x & 63;
    int m = l & 15, q8 = (l >> 4) * 8;
#pragma unroll
    for (int kc = 0; kc < 128; kc += 32) {
        short8x av = *(const short8x*)&A[m][kc + q8];
        short8x b0 = *(const short8x*)&B[n0 + m][kc + q8];
        short8x b1 = *(const short8x*)&B[n0 + 16 + m][kc + q8];
        a0 = __builtin_amdgcn_mfma_f32_16x16x32_bf16(av, b0, a0, 0, 0, 0);
        a1 = __builtin_amdgcn_mfma_f32_16x16x32_bf16(av, b1, a1, 0, 0, 0);
    }
}

__global__ __launch_bounds__(NTHR, 2) void k_mega(P p) {
    __shared__ u16 Wt[128][136];      // 34816 B
    __shared__ u16 Ab[MR][136];       // 4352
    __shared__ u16 Tb[MR][136];       // 4352
    __shared__ float Hf[MR][132];     // 8448
    __shared__ float red[16];
    int tid = threadIdx.x, blk = blockIdx.x;
    int gid = blk * NTHR + tid;
    int l = tid & 63, w = tid >> 6;
    int m = l & 15, q4 = l >> 4, q8 = q4 * 8;
    int r0 = blk * MR;

    // ================= phase 0: prep (transpose weights, zero cnt/out) ======
    for (int id = gid; id < 12 * 16384; id += GRID * NTHR) {
        int which = id >> 14;
        int r = id & 16383;
        int n = r >> 7, k = r & 127;
        const float* src = which < 4 ? p.liw : (which < 8 ? p.nw1 : p.nw2);
        u16* dst = which < 4 ? p.liwT : (which < 8 ? p.nw1T : p.nw2T);
        int b = which & 3;
        dst[b * 16384 + n * 128 + k] = f2bf(src[(size_t)b * 16384 + k * 128 + n]);
    }
    if (gid < 8192) {
        p.cnt[gid] = 0;
        int n = gid >> 7, k = gid & 127;   // n < 64
        p.ro1T[n * 128 + k] = f2bf(p.rw1[k * 64 + n]);
        if (gid < p.out_n) p.out[gid] = 0.0f;
    }
    gbar(&p.bar[0]);

    // ================= phase 1: edges + lutall + embed/x0 ===================
    for (int e = gid; e < EE; e += GRID * NTHR) {
        int s = p.ei[e];
        int d = p.ei[EE + e];
        float dx = p.pos[s * 3 + 0] - p.pos[d * 3 + 0];
        float dy = p.pos[s * 3 + 1] - p.pos[d * 3 + 1];
        float dz = p.pos[s * 3 + 2] - p.pos[d * 3 + 2];
        float dist = fminf(sqrtf(dx * dx + dy * dy + dz * dz), RCUTF);
        float f = dist * ((TLUT - 1) / RCUTF);
        int i0 = (int)f;
        i0 = i0 > TLUT - 2 ? TLUT - 2 : i0;
        float fr = f - (float)i0;
        int y = (i0 << 16) | (int)(fr * 65535.0f);
        int pslot = atomicAdd(&p.cnt[d], 1);
        if (pslot < CAP) p.meta[(size_t)d * CAP + pslot] = make_int2(s, y);
    }

    if (blk < 128) {   // filter-LUT MLP: 4 nets x 32 row-tiles
        float* As = (float*)Hf;              // [32][33]
        float* Ws = (float*)Wt;              // [32][128]
        float* T2 = (float*)Wt + 4096;       // [32][128]
        int blk_b = blk >> 5;
        int r0l = (blk & 31) * 32;
        const float* W1 = p.ew1 + (size_t)blk_b * NRBF * HIDD;
        const float* b1 = p.eb1 + blk_b * HIDD;
        const float* W2 = p.ew2 + (size_t)blk_b * HIDD * HIDD;
        const float* b2 = p.eb2 + blk_b * HIDD;
        u16* lutp = p.lutall + (size_t)blk_b * TLUT * 256;
        int tx = tid & 31, ty = tid >> 5;
        int c0 = tx * 4, rr = ty * 4;
        float acc[4][4] = {};
        for (int kc = 0; kc < NRBF; kc += 32) {
            int lr = tid >> 3, lc = (tid & 7) * 4;
            float dt = (r0l + lr) * (RCUTF / (TLUT - 1));
#pragma unroll
            for (int j = 0; j < 4; ++j) {
                float c = (kc + lc + j) * (RCUTF / 63.0f);
                float u = dt - c;
                As[lr * 33 + lc + j] = __expf(-GAMMAF * u * u);
            }
#pragma unroll
            for (int j = 0; j < 4; ++j) {
                int idx = tid + j * 256;
                int wr = idx >> 5, wc = (idx & 31) * 4;
                *(float4*)&Ws[wr * 128 + wc] =
                    *(const float4*)&W1[(size_t)(kc + wr) * HIDD + wc];
            }
            __syncthreads();
#pragma unroll 8
            for (int k = 0; k < 32; ++k) {
                float4 wv = *(float4*)&Ws[k * 128 + c0];
                float a0 = As[(rr + 0) * 33 + k], a1 = As[(rr + 1) * 33 + k];
                float a2 = As[(rr + 2) * 33 + k], a3 = As[(rr + 3) * 33 + k];
                acc[0][0] += a0 * wv.x; acc[0][1] += a0 * wv.y; acc[0][2] += a0 * wv.z; acc[0][3] += a0 * wv.w;
                acc[1][0] += a1 * wv.x; acc[1][1] += a1 * wv.y; acc[1][2] += a1 * wv.z; acc[1][3] += a1 * wv.w;
                acc[2][0] += a2 * wv.x; acc[2][1] += a2 * wv.y; acc[2][2] += a2 * wv.z; acc[2][3] += a2 * wv.w;
                acc[3][0] += a3 * wv.x; acc[3][1] += a3 * wv.y; acc[3][2] += a3 * wv.z; acc[3][3] += a3 * wv.w;
            }
            __syncthreads();
        }
#pragma unroll
        for (int i = 0; i < 4; ++i)
#pragma unroll
            for (int j = 0; j < 4; ++j)
                T2[(rr + i) * 128 + c0 + j] = silu_f(acc[i][j] + b1[c0 + j]);
        float acc2[4][4] = {};
        __syncthreads();
        for (int kc = 0; kc < HIDD; kc += 32) {
#pragma unroll
            for (int j = 0; j < 4; ++j) {
                int idx = tid + j * 256;
                int wr = idx >> 5, wc = (idx & 31) * 4;
                *(float4*)&Ws[wr * 128 + wc] =
                    *(const float4*)&W2[(size_t)(kc + wr) * HIDD + wc];
            }
            __syncthreads();
#pragma unroll 8
            for (int k = 0; k < 32; ++k) {
                float4 wv = *(float4*)&Ws[k * 128 + c0];
                float a0 = T2[(rr + 0) * 128 + kc + k], a1 = T2[(rr + 1) * 128 + kc + k];
                float a2 = T2[(rr + 2) * 128 + kc + k], a3 = T2[(rr + 3) * 128 + kc + k];
                acc2[0][0] += a0 * wv.x; acc2[0][1] += a0 * wv.y; acc2[0][2] += a0 * wv.z; acc2[0][3] += a0 * wv.w;
                acc2[1][0] += a1 * wv.x; acc2[1][1] += a1 * wv.y; acc2[1][2] += a1 * wv.z; acc2[1][3] += a1 * wv.w;
                acc2[2][0] += a2 * wv.x; acc2[2][1] += a2 * wv.y; acc2[2][2] += a2 * wv.z; acc2[2][3] += a2 * wv.w;
                acc2[3][0] += a3 * wv.x; acc2[3][1] += a3 * wv.y; acc2[3][2] += a3 * wv.z; acc2[3][3] += a3 * wv.w;
            }
            __syncthreads();
        }
#pragma unroll
        for (int i = 0; i < 4; ++i) {
            int t = r0l + rr + i;
            ushort2 a01, a23;
            a01.x = f2bf(acc2[i][0] + b2[c0 + 0]);
            a01.y = f2bf(acc2[i][1] + b2[c0 + 1]);
            a23.x = f2bf(acc2[i][2] + b2[c0 + 2]);
            a23.y = f2bf(acc2[i][3] + b2[c0 + 3]);
            u16* pa = lutp + ((size_t)t * 64 + (c0 >> 1)) * 4;
            *(ushort2*)(pa + 0) = a01;
            *(ushort2*)(pa + 4) = a23;
            if (t > 0) {
                u16* pb = lutp + ((size_t)(t - 1) * 64 + (c0 >> 1)) * 4;
                *(ushort2*)(pb + 2) = a01;
                *(ushort2*)(pb + 6) = a23;
            }
        }
        __syncthreads();
    }

    // embed + x0 = h @ liwT[0] for this block's 16 rows
    {
        int row = tid >> 4, c8 = (tid & 15) * 8;
        int z = p.Z[r0 + row];
        const float* er = p.ew + (size_t)z * HIDD + c8;
        float* hr = p.h + (size_t)(r0 + row) * HIDD + c8;
        float4 v0 = *(const float4*)er;
        float4 v1 = *(const float4*)(er + 4);
        *(float4*)hr = v0;
        *(float4*)(hr + 4) = v1;
        ushort4 a0, a1;
        a0.x = f2bf(v0.x); a0.y = f2bf(v0.y); a0.z = f2bf(v0.z); a0.w = f2bf(v0.w);
        a1.x = f2bf(v1.x); a1.y = f2bf(v1.y); a1.z = f2bf(v1.z); a1.w = f2bf(v1.w);
        *(ushort4*)&Ab[row][c8] = a0;
        *(ushort4*)&Ab[row][c8 + 4] = a1;
    }
    stage_wt(Wt, p.liwT, 128);
    __syncthreads();
    {
        f32x4 a0 = {0, 0, 0, 0}, a1 = {0, 0, 0, 0};
        gemm16(Ab, Wt, w * 32, a0, a1);
        int c = w * 32 + m;
#pragma unroll
        for (int r = 0; r < 4; ++r) {
            int row = q4 * 4 + r;
            u16* xr = p.xb0 + (size_t)(r0 + row) * HIDD;
            xr[c] = f2bf(a0[r]);
            xr[c + 16] = f2bf(a1[r]);
        }
    }
    gbar(&p.bar[1]);

    // ================= 4 message-passing iterations =========================
    for (int it = 0; it < NBLK; ++it) {
        int last = (it == NBLK - 1);
        const u16* lutb = p.lutall + (size_t)it * TLUT * 256;
        const u16* xin = (it & 1) ? p.xb1 : p.xb0;
        u16* xout = (it & 1) ? p.xb0 : p.xb1;
        const u16* w1t = p.nw1T + (size_t)it * HIDD * HIDD;
        const u16* w2t = p.nw2T + (size_t)it * HIDD * HIDD;
        const float* b1 = p.nb1 + it * HIDD;
        const float* b2 = p.nb2 + it * HIDD;
        const float* g = p.lng + it * HIDD;
        const float* bb = p.lnb + it * HIDD;
        const u16* w3t = last ? p.ro1T : p.liwT + (size_t)(it + 1) * HIDD * HIDD;

        // --- gather: this block's 16 dst rows, agg -> Ab (LDS, bf16) --------
#pragma unroll
        for (int dd = 0; dd < 4; ++dd) {
            int dst = r0 + w * 4 + dd;
            int n = p.cnt[dst];
            n = n > CAP ? CAP : n;
            const int2* mp = p.meta + (size_t)dst * CAP;
            int nm1 = n > 0 ? n - 1 : 0;
            int2 mdA = mp[l < nm1 ? l : nm1];
            int2 mdB = mp[64 + l < nm1 ? 64 + l : nm1];
            float ax = 0.0f, ay = 0.0f;
#pragma unroll 4
            for (int t = 0; t < n; ++t) {
                int mx = __builtin_amdgcn_readlane(t < 64 ? mdA.x : mdB.x, t & 63);
                int my = __builtin_amdgcn_readlane(t < 64 ? mdA.y : mdB.y, t & 63);
                int i0 = my >> 16;
                float fr = (my & 0xffff) * (1.0f / 65535.0f);
                ushort4 lv = *(const ushort4*)&lutb[(((size_t)i0 << 6) + l) << 2];
                ushort2 xv = *(const ushort2*)&xin[((size_t)mx << 7) + 2 * l];
                float w0x = bf2f(lv.x), w0y = bf2f(lv.y);
                float wx = fmaf(fr, bf2f(lv.z) - w0x, w0x);
                float wy = fmaf(fr, bf2f(lv.w) - w0y, w0y);
                ax = fmaf(wx, bf2f(xv.x), ax);
                ay = fmaf(wy, bf2f(xv.y), ay);
            }
            ushort2 o;
            o.x = f2bf(ax);
            o.y = f2bf(ay);
            *(ushort2*)&Ab[w * 4 + dd][2 * l] = o;
        }
        stage_wt(Wt, w1t, 128);
        __syncthreads();

        // --- GEMM1: T = silu(agg @ W1 + b1) ---------------------------------
        {
            f32x4 a0 = {0, 0, 0, 0}, a1 = {0, 0, 0, 0};
            gemm16(Ab, Wt, w * 32, a0, a1);
            int c = w * 32 + m;
            float bv0 = b1[c], bv1 = b1[c + 16];
            __syncthreads();   // all waves done reading Wt/Ab
#pragma unroll
            for (int r = 0; r < 4; ++r) {
                int row = q4 * 4 + r;
                Tb[row][c] = f2bf(silu_f(a0[r] + bv0));
                Tb[row][c + 16] = f2bf(silu_f(a1[r] + bv1));
            }
        }
        stage_wt(Wt, w2t, 128);
        __syncthreads();

        // --- GEMM2: Hf = T @ W2 + b2 + h (residual) -------------------------
        {
            f32x4 a0 = {0, 0, 0, 0}, a1 = {0, 0, 0, 0};
            gemm16(Tb, Wt, w * 32, a0, a1);
            int c = w * 32 + m;
            float bv0 = b2[c], bv1 = b2[c + 16];
            __syncthreads();   // done reading Wt/Tb
#pragma unroll
            for (int r = 0; r < 4; ++r) {
                int row = q4 * 4 + r;
                const float* hr = p.h + (size_t)(r0 + row) * HIDD;
                Hf[row][c] = a0[r] + bv0 + hr[c];
                Hf[row][c + 16] = a1[r] + bv1 + hr[c + 16];
            }
        }
        stage_wt(Wt, w3t, last ? 64 : 128);
        __syncthreads();

        // --- LN + write h; Ab = bf16(h') or bf16(silu(h')) ------------------
        {
            float gx = g[2 * l], gy = g[2 * l + 1];
            float bx = bb[2 * l], by = bb[2 * l + 1];
#pragma unroll
            for (int rr = 0; rr < 4; ++rr) {
                int row = w * 4 + rr;
                float2 v = *(float2*)&Hf[row][2 * l];
                float s = v.x + v.y;
#pragma unroll
                for (int mm = 32; mm; mm >>= 1) s += __shfl_xor(s, mm);
                float mu = s * (1.0f / 128.0f);
                float dx = v.x - mu, dy = v.y - mu;
                float qq = dx * dx + dy * dy;
#pragma unroll
                for (int mm = 32; mm; mm >>= 1) qq += __shfl_xor(qq, mm);
                float rstd = rsqrtf(qq * (1.0f / 128.0f) + 1e-5f);
                float ox = dx * rstd * gx + bx;
                float oy = dy * rstd * gy + by;
                if (!last) {
                    float2 o;
                    o.x = ox;
                    o.y = oy;
                    *(float2*)&p.h[(size_t)(r0 + row) * HIDD + 2 * l] = o;
                }
                ushort2 a;
                a.x = f2bf(last ? silu_f(ox) : ox);
                a.y = f2bf(last ? silu_f(oy) : oy);
                *(ushort2*)&Ab[row][2 * l] = a;
            }
        }
        __syncthreads();

        // --- GEMM3: next x   OR   readout -----------------------------------
        if (!last) {
            f32x4 a0 = {0, 0, 0, 0}, a1 = {0, 0, 0, 0};
            gemm16(Ab, Wt, w * 32, a0, a1);
            int c = w * 32 + m;
#pragma unroll
            for (int r = 0; r < 4; ++r) {
                int row = q4 * 4 + r;
                u16* xr = xout + (size_t)(r0 + row) * HIDD;
                xr[c] = f2bf(a0[r]);
                xr[c + 16] = f2bf(a1[r]);
            }
            gbar(&p.bar[2 + it]);   // xout visible before next gather
        } else {
            f32x4 a0 = {0, 0, 0, 0};
#pragma unroll
            for (int kc = 0; kc < 128; kc += 32) {
                short8x av = *(const short8x*)&Ab[m][kc + q8];
                short8x bv = *(const short8x*)&Wt[w * 16 + m][kc + q8];
                a0 = __builtin_amdgcn_mfma_f32_16x16x32_bf16(av, bv, a0, 0, 0, 0);
            }
            int c = w * 16 + m;
            float bv = p.rb1[c], wv = p.rw2[c];
            float tsum = 0.0f;
#pragma unroll
            for (int r = 0; r < 4; ++r) tsum += silu_f(a0[r] + bv) * wv;
#pragma unroll
            for (int mm = 32; mm; mm >>= 1) tsum += __shfl_xor(tsum, mm);
            if (l == 0) red[w] = tsum;
            __syncthreads();
            if (tid == 0) {
                float tot = red[0] + red[1] + red[2] + red[3] + (float)MR * p.rb2[0];
                atomicAdd(&p.out[blk >> 3], tot);
            }
        }
    }
}

extern "C" void kernel_launch(void* const* d_in, const int* in_sizes, int n_in,
                              void* d_out, int out_size, void* d_ws, size_t ws_size,
                              hipStream_t stream) {
    P prm;
    prm.Z   = (const int*)d_in[0];
    prm.pos = (const float*)d_in[1];
    prm.ei  = (const int*)d_in[2];
    prm.ew  = (const float*)d_in[3];
    prm.ew1 = (const float*)d_in[4];
    prm.eb1 = (const float*)d_in[5];
    prm.ew2 = (const float*)d_in[6];
    prm.eb2 = (const float*)d_in[7];
    prm.liw = (const float*)d_in[8];
    prm.nw1 = (const float*)d_in[9];
    prm.nb1 = (const float*)d_in[10];
    prm.nw2 = (const float*)d_in[11];
    prm.nb2 = (const float*)d_in[12];
    prm.lng = (const float*)d_in[13];
    prm.lnb = (const float*)d_in[14];
    prm.rw1 = (const float*)d_in[15];
    prm.rb1 = (const float*)d_in[16];
    prm.rw2 = (const float*)d_in[17];
    prm.rb2 = (const float*)d_in[18];
    prm.out = (float*)d_out;
    prm.out_n = out_size;

    float* h      = (float*)d_ws;                            // 4 MB
    u16*   xb0    = (u16*)(h + (size_t)BN * HIDD);           // 2 MB
    u16*   xb1    = xb0 + (size_t)BN * HIDD;                 // 2 MB
    u16*   lutall = xb1 + (size_t)BN * HIDD;                 // 2 MB (interleaved)
    u16*   liwT   = lutall + (size_t)NBLK * TLUT * 256;      // 128 KB
    u16*   nw1T   = liwT + (size_t)NBLK * HIDD * HIDD;
    u16*   nw2T   = nw1T + (size_t)NBLK * HIDD * HIDD;
    u16*   ro1T   = nw2T + (size_t)NBLK * HIDD * HIDD;       // 16 KB
    int*   cnt    = (int*)(ro1T + 64 * HIDD);                // 32 KB
    int2*  meta   = (int2*)(cnt + BN);                       // 8 MB
    int*   bar    = (int*)(meta + (size_t)BN * CAP);         // 32 B

    prm.h = h; prm.xb0 = xb0; prm.xb1 = xb1; prm.lutall = lutall;
    prm.liwT = liwT; prm.nw1T = nw1T; prm.nw2T = nw2T; prm.ro1T = ro1T;
    prm.cnt = cnt; prm.meta = meta; prm.bar = bar;

    hipMemsetAsync(bar, 0, 8 * sizeof(int), stream);
    k_mega<<<GRID, NTHR, 0, stream>>>(prm);
}

// Round 7
// 289.270 us; speedup vs baseline: 2.4967x; 2.4967x over previous
//
#include <hip/hip_runtime.h>

#define BN 8192
#define EE 262144
#define HIDD 128
#define NRBF 64
#define NBLK 4
#define TLUT 2048
#define CAP 128
#define MROWS 32
#define MR 16
#define RCUTF 6.0f
#define GAMMAF (10.0f / 36.0f)

typedef unsigned short u16;
typedef __attribute__((ext_vector_type(8))) short short8x;
typedef __attribute__((ext_vector_type(4))) float f32x4;

__device__ __forceinline__ float silu_f(float v) {
    return v / (1.0f + __expf(-v));
}
__device__ __forceinline__ float bf2f(u16 u) {
    return __uint_as_float(((unsigned)u) << 16);
}
__device__ __forceinline__ u16 f2bf(float f) {
    unsigned u = __float_as_uint(f);
    unsigned r = u + 0x7FFFu + ((u >> 16) & 1u);
    return (u16)(r >> 16);
}

// ---- MFMA helpers (B pre-transposed [n][k], LDS stride 136) -----------------
__device__ __forceinline__ void stage_wt(u16 Wt[][136], const u16* __restrict__ src,
                                         int rows) {
    int tid = threadIdx.x;
    int chunks = rows * 16;
    for (int idx = tid; idx < chunks; idx += 256) {
        int r = idx >> 4, c = (idx & 15) * 8;
        *(float4*)&Wt[r][c] = *(const float4*)&src[r * HIDD + c];
    }
}

// C[16 x 32] per wave
__device__ __forceinline__ void gemm16(const u16 A[][136], const u16 B[][136],
                                       int n0, f32x4& a0, f32x4& a1) {
    int l = threadIdx.x & 63;
    int m = l & 15, q8 = (l >> 4) * 8;
#pragma unroll
    for (int kc = 0; kc < 128; kc += 32) {
        short8x av = *(const short8x*)&A[m][kc + q8];
        short8x b0 = *(const short8x*)&B[n0 + m][kc + q8];
        short8x b1 = *(const short8x*)&B[n0 + 16 + m][kc + q8];
        a0 = __builtin_amdgcn_mfma_f32_16x16x32_bf16(av, b0, a0, 0, 0, 0);
        a1 = __builtin_amdgcn_mfma_f32_16x16x32_bf16(av, b1, a1, 0, 0, 0);
    }
}

// C[32 x 32] per wave
__device__ __forceinline__ void gemm32(const u16 A[][136], const u16 B[][136],
                                       int n0, f32x4 acc[2][2]) {
    int l = threadIdx.x & 63;
    int m = l & 15, q8 = (l >> 4) * 8;
#pragma unroll
    for (int kc = 0; kc < 128; kc += 32) {
        short8x a0 = *(const short8x*)&A[m][kc + q8];
        short8x a1 = *(const short8x*)&A[16 + m][kc + q8];
        short8x b0 = *(const short8x*)&B[n0 + m][kc + q8];
        short8x b1 = *(const short8x*)&B[n0 + 16 + m][kc + q8];
        acc[0][0] = __builtin_amdgcn_mfma_f32_16x16x32_bf16(a0, b0, acc[0][0], 0, 0, 0);
        acc[0][1] = __builtin_amdgcn_mfma_f32_16x16x32_bf16(a0, b1, acc[0][1], 0, 0, 0);
        acc[1][0] = __builtin_amdgcn_mfma_f32_16x16x32_bf16(a1, b0, acc[1][0], 0, 0, 0);
        acc[1][1] = __builtin_amdgcn_mfma_f32_16x16x32_bf16(a1, b1, acc[1][1], 0, 0, 0);
    }
}

// ---- k_setup: edges | LUT-MLP | embed+x0 | weight transposes (independent) --
__global__ __launch_bounds__(256) void k_setup(
    const int* __restrict__ Z, const float* __restrict__ pos,
    const int* __restrict__ ei, const float* __restrict__ ew,
    const float* __restrict__ ew1, const float* __restrict__ eb1,
    const float* __restrict__ ew2, const float* __restrict__ eb2,
    const float* __restrict__ liw, const float* __restrict__ nw1,
    const float* __restrict__ nw2, const float* __restrict__ ro1,
    int* __restrict__ cnt, int* __restrict__ meta, u16* __restrict__ lutall,
    float* __restrict__ h, u16* __restrict__ xb0,
    u16* __restrict__ liwT, u16* __restrict__ nw1T, u16* __restrict__ nw2T,
    u16* __restrict__ ro1T, float* __restrict__ out, int out_n) {
    __shared__ union {
        struct { u16 Wt[128][136]; u16 Ab[MR][136]; } ex;          // 39168 B
        struct { float As[32 * 33]; float Ws[32 * 128]; float T2[32 * 128]; } lu;
    } S;
    int tid = threadIdx.x, blk = blockIdx.x;

    if (blk < 1024) {
        // ---------------- edges: bucket by dst, pack (i0<<13 | src) ---------
        int e = blk * 256 + tid;
        int s = ei[e];
        int d = ei[EE + e];
        float dx = pos[s * 3 + 0] - pos[d * 3 + 0];
        float dy = pos[s * 3 + 1] - pos[d * 3 + 1];
        float dz = pos[s * 3 + 2] - pos[d * 3 + 2];
        float dist = fminf(sqrtf(dx * dx + dy * dy + dz * dz), RCUTF);
        int i0 = (int)(dist * ((TLUT - 1) / RCUTF) + 0.5f);
        i0 = i0 > TLUT - 1 ? TLUT - 1 : i0;
        int p = atomicAdd(&cnt[d], 1);
        if (p < CAP) meta[(size_t)d * CAP + p] = (i0 << 13) | s;
    } else if (blk < 1280) {
        // ---------------- filter LUT: 4 nets x 64 row-tiles of 32 -----------
        int lb = blk - 1024;
        int net = lb >> 6;
        int r0l = (lb & 63) * 32;
        const float* W1 = ew1 + (size_t)net * NRBF * HIDD;
        const float* b1 = eb1 + net * HIDD;
        const float* W2 = ew2 + (size_t)net * HIDD * HIDD;
        const float* b2 = eb2 + net * HIDD;
        u16* lutp = lutall + (size_t)net * TLUT * HIDD;
        int tx = tid & 31, ty = tid >> 5;
        int c0 = tx * 4, rr = ty * 4;
        float acc[4][4] = {};
        for (int kc = 0; kc < NRBF; kc += 32) {
            int lr = tid >> 3, lc = (tid & 7) * 4;
            float dt = (r0l + lr) * (RCUTF / (TLUT - 1));
#pragma unroll
            for (int j = 0; j < 4; ++j) {
                float c = (kc + lc + j) * (RCUTF / 63.0f);
                float u = dt - c;
                S.lu.As[lr * 33 + lc + j] = __expf(-GAMMAF * u * u);
            }
#pragma unroll
            for (int j = 0; j < 4; ++j) {
                int idx = tid + j * 256;
                int wr = idx >> 5, wc = (idx & 31) * 4;
                *(float4*)&S.lu.Ws[wr * 128 + wc] =
                    *(const float4*)&W1[(size_t)(kc + wr) * HIDD + wc];
            }
            __syncthreads();
#pragma unroll 8
            for (int k = 0; k < 32; ++k) {
                float4 wv = *(float4*)&S.lu.Ws[k * 128 + c0];
                float a0 = S.lu.As[(rr + 0) * 33 + k];
                float a1 = S.lu.As[(rr + 1) * 33 + k];
                float a2 = S.lu.As[(rr + 2) * 33 + k];
                float a3 = S.lu.As[(rr + 3) * 33 + k];
                acc[0][0] += a0 * wv.x; acc[0][1] += a0 * wv.y; acc[0][2] += a0 * wv.z; acc[0][3] += a0 * wv.w;
                acc[1][0] += a1 * wv.x; acc[1][1] += a1 * wv.y; acc[1][2] += a1 * wv.z; acc[1][3] += a1 * wv.w;
                acc[2][0] += a2 * wv.x; acc[2][1] += a2 * wv.y; acc[2][2] += a2 * wv.z; acc[2][3] += a2 * wv.w;
                acc[3][0] += a3 * wv.x; acc[3][1] += a3 * wv.y; acc[3][2] += a3 * wv.z; acc[3][3] += a3 * wv.w;
            }
            __syncthreads();
        }
#pragma unroll
        for (int i = 0; i < 4; ++i)
#pragma unroll
            for (int j = 0; j < 4; ++j)
                S.lu.T2[(rr + i) * 128 + c0 + j] = silu_f(acc[i][j] + b1[c0 + j]);
        float acc2[4][4] = {};
        __syncthreads();
        for (int kc = 0; kc < HIDD; kc += 32) {
#pragma unroll
            for (int j = 0; j < 4; ++j) {
                int idx = tid + j * 256;
                int wr = idx >> 5, wc = (idx & 31) * 4;
                *(float4*)&S.lu.Ws[wr * 128 + wc] =
                    *(const float4*)&W2[(size_t)(kc + wr) * HIDD + wc];
            }
            __syncthreads();
#pragma unroll 8
            for (int k = 0; k < 32; ++k) {
                float4 wv = *(float4*)&S.lu.Ws[k * 128 + c0];
                float a0 = S.lu.T2[(rr + 0) * 128 + kc + k];
                float a1 = S.lu.T2[(rr + 1) * 128 + kc + k];
                float a2 = S.lu.T2[(rr + 2) * 128 + kc + k];
                float a3 = S.lu.T2[(rr + 3) * 128 + kc + k];
                acc2[0][0] += a0 * wv.x; acc2[0][1] += a0 * wv.y; acc2[0][2] += a0 * wv.z; acc2[0][3] += a0 * wv.w;
                acc2[1][0] += a1 * wv.x; acc2[1][1] += a1 * wv.y; acc2[1][2] += a1 * wv.z; acc2[1][3] += a1 * wv.w;
                acc2[2][0] += a2 * wv.x; acc2[2][1] += a2 * wv.y; acc2[2][2] += a2 * wv.z; acc2[2][3] += a2 * wv.w;
                acc2[3][0] += a3 * wv.x; acc2[3][1] += a3 * wv.y; acc2[3][2] += a3 * wv.z; acc2[3][3] += a3 * wv.w;
            }
            __syncthreads();
        }
#pragma unroll
        for (int i = 0; i < 4; ++i) {
            int t = r0l + rr + i;
            ushort4 o;
            o.x = f2bf(acc2[i][0] + b2[c0 + 0]);
            o.y = f2bf(acc2[i][1] + b2[c0 + 1]);
            o.z = f2bf(acc2[i][2] + b2[c0 + 2]);
            o.w = f2bf(acc2[i][3] + b2[c0 + 3]);
            *(ushort4*)&lutp[(size_t)t * HIDD + c0] = o;
        }
    } else if (blk < 1792) {
        // ---------------- embed + x0 = h @ liw[0] (inline transpose) --------
        int r0 = (blk - 1280) * MR;
        for (int idx = tid; idx < 16384; idx += 256) {
            int n = idx & 127, k = idx >> 7;
            S.ex.Wt[n][k] = f2bf(liw[(size_t)k * 128 + n]);
        }
        {
            int row = tid >> 4, c8 = (tid & 15) * 8;
            int z = Z[r0 + row];
            const float* er = ew + (size_t)z * HIDD + c8;
            float* hr = h + (size_t)(r0 + row) * HIDD + c8;
            float4 v0 = *(const float4*)er;
            float4 v1 = *(const float4*)(er + 4);
            *(float4*)hr = v0;
            *(float4*)(hr + 4) = v1;
            ushort4 a0, a1;
            a0.x = f2bf(v0.x); a0.y = f2bf(v0.y); a0.z = f2bf(v0.z); a0.w = f2bf(v0.w);
            a1.x = f2bf(v1.x); a1.y = f2bf(v1.y); a1.z = f2bf(v1.z); a1.w = f2bf(v1.w);
            *(ushort4*)&S.ex.Ab[row][c8] = a0;
            *(ushort4*)&S.ex.Ab[row][c8 + 4] = a1;
        }
        __syncthreads();
        int w = tid >> 6, l = tid & 63;
        int m = l & 15, q4 = l >> 4;
        f32x4 a0 = {0, 0, 0, 0}, a1 = {0, 0, 0, 0};
        gemm16(S.ex.Ab, S.ex.Wt, w * 32, a0, a1);
        int c = w * 32 + m;
#pragma unroll
        for (int r = 0; r < 4; ++r) {
            int row = q4 * 4 + r;
            u16* xr = xb0 + (size_t)(r0 + row) * HIDD;
            xr[c] = f2bf(a0[r]);
            xr[c + 16] = f2bf(a1[r]);
        }
    } else {
        // ---------------- weight transposes + out zero ----------------------
        for (int id = (blk - 1792) * 256 + tid; id < 188416; id += 128 * 256) {
            if (id < 180224) {
                int which = id >> 14;       // 0..10
                int r = id & 16383;
                int n = r >> 7, k = r & 127;
                const float* src;
                u16* dst;
                if (which < 3) { src = liw + (size_t)(which + 1) * 16384;
                                 dst = liwT + (size_t)(which + 1) * 16384; }
                else if (which < 7) { src = nw1 + (size_t)(which - 3) * 16384;
                                      dst = nw1T + (size_t)(which - 3) * 16384; }
                else { src = nw2 + (size_t)(which - 7) * 16384;
                       dst = nw2T + (size_t)(which - 7) * 16384; }
                dst[n * 128 + k] = f2bf(src[(size_t)k * 128 + n]);
            } else {
                int rid = id - 180224;      // [0, 8192)
                int n = rid >> 7, k = rid & 127;
                ro1T[n * 128 + k] = f2bf(ro1[(size_t)k * 64 + n]);
            }
        }
        if (blk == 1792 && tid < out_n) out[tid] = 0.0f;
    }
}

// ---- gather: one wave per dst, reg-preloaded meta, nearest-LUT --------------
__global__ __launch_bounds__(256, 4) void k_agg(const int* __restrict__ cnt,
                                                const int* __restrict__ meta,
                                                const u16* __restrict__ lut,
                                                const u16* __restrict__ xin,
                                                u16* __restrict__ aggb) {
    int dst = blockIdx.x * 4 + (threadIdx.x >> 6);
    int l = threadIdx.x & 63;
    int n = cnt[dst];
    n = n > CAP ? CAP : n;
    const int* mp = meta + (size_t)dst * CAP;
    int nm1 = n > 0 ? n - 1 : 0;
    int mA = mp[l < nm1 ? l : nm1];
    int mB = mp[64 + l < nm1 ? 64 + l : nm1];
    float ax = 0.0f, ay = 0.0f;
#pragma unroll 4
    for (int t = 0; t < n; ++t) {
        int md = __shfl(t < 64 ? mA : mB, t & 63);
        int s = md & 8191;
        int i0 = md >> 13;
        ushort2 lv = *(const ushort2*)&lut[((size_t)i0 << 7) + 2 * l];
        ushort2 xv = *(const ushort2*)&xin[((size_t)s << 7) + 2 * l];
        ax = fmaf(bf2f(lv.x), bf2f(xv.x), ax);
        ay = fmaf(bf2f(lv.y), bf2f(xv.y), ay);
    }
    ushort2 o;
    o.x = f2bf(ax);
    o.y = f2bf(ay);
    *(ushort2*)&aggb[((size_t)dst << 7) + 2 * l] = o;
}

// ---- fused node MLP + LN + (next-x | readout), MFMA ------------------------
__global__ __launch_bounds__(256, 2) void k_mlp(
    const u16* __restrict__ aggb, float* __restrict__ h,
    const u16* __restrict__ w1t, const float* __restrict__ b1,
    const u16* __restrict__ w2t, const float* __restrict__ b2,
    const float* __restrict__ g, const float* __restrict__ bb,
    const u16* __restrict__ w3t, u16* __restrict__ xout, int last,
    const float* __restrict__ rb1, const float* __restrict__ rw2,
    const float* __restrict__ rb2, float* __restrict__ out) {
    __shared__ u16 Wt[128][136];
    __shared__ u16 Ab[MROWS][136];
    __shared__ u16 Tb[MROWS][136];
    __shared__ float Hf[MROWS][132];
    __shared__ float red[4];
    int tid = threadIdx.x;
    int w = tid >> 6, l = tid & 63;
    int m = l & 15, q4 = l >> 4, q8 = q4 * 8;
    int r0 = blockIdx.x * MROWS;

    {
        int row = tid >> 3, c8 = (tid & 7) * 16;
        const u16* ar = aggb + ((size_t)(r0 + row) << 7) + c8;
        *(float4*)&Ab[row][c8] = *(const float4*)ar;
        *(float4*)&Ab[row][c8 + 8] = *(const float4*)(ar + 8);
    }
    stage_wt(Wt, w1t, 128);
    __syncthreads();

    {
        f32x4 acc[2][2] = {{{0, 0, 0, 0}, {0, 0, 0, 0}}, {{0, 0, 0, 0}, {0, 0, 0, 0}}};
        gemm32(Ab, Wt, w * 32, acc);
        int c = w * 32 + m;
        float bv0 = b1[c], bv1 = b1[c + 16];
        __syncthreads();
#pragma unroll
        for (int half = 0; half < 2; ++half)
#pragma unroll
            for (int r = 0; r < 4; ++r) {
                int row = half * 16 + q4 * 4 + r;
                Tb[row][c] = f2bf(silu_f(acc[half][0][r] + bv0));
                Tb[row][c + 16] = f2bf(silu_f(acc[half][1][r] + bv1));
            }
    }
    stage_wt(Wt, w2t, 128);
    __syncthreads();

    {
        f32x4 acc[2][2] = {{{0, 0, 0, 0}, {0, 0, 0, 0}}, {{0, 0, 0, 0}, {0, 0, 0, 0}}};
        gemm32(Tb, Wt, w * 32, acc);
        int c = w * 32 + m;
        float bv0 = b2[c], bv1 = b2[c + 16];
        __syncthreads();
#pragma unroll
        for (int half = 0; half < 2; ++half)
#pragma unroll
            for (int r = 0; r < 4; ++r) {
                int row = half * 16 + q4 * 4 + r;
                const float* hr = h + (size_t)(r0 + row) * HIDD;
                Hf[row][c] = acc[half][0][r] + bv0 + hr[c];
                Hf[row][c + 16] = acc[half][1][r] + bv1 + hr[c + 16];
            }
    }
    stage_wt(Wt, w3t, last ? 64 : 128);
    __syncthreads();

    {
        float gx = g[2 * l], gy = g[2 * l + 1];
        float bx = bb[2 * l], by = bb[2 * l + 1];
#pragma unroll
        for (int rr = 0; rr < 8; ++rr) {
            int row = w * 8 + rr;
            float2 v = *(float2*)&Hf[row][2 * l];
            float s = v.x + v.y;
#pragma unroll
            for (int mm = 32; mm; mm >>= 1) s += __shfl_xor(s, mm);
            float mu = s * (1.0f / 128.0f);
            float dx = v.x - mu, dy = v.y - mu;
            float qq = dx * dx + dy * dy;
#pragma unroll
            for (int mm = 32; mm; mm >>= 1) qq += __shfl_xor(qq, mm);
            float rstd = rsqrtf(qq * (1.0f / 128.0f) + 1e-5f);
            float ox = dx * rstd * gx + bx;
            float oy = dy * rstd * gy + by;
            if (!last) {
                float2 o;
                o.x = ox;
                o.y = oy;
                *(float2*)&h[(size_t)(r0 + row) * HIDD + 2 * l] = o;
            }
            ushort2 a;
            a.x = f2bf(last ? silu_f(ox) : ox);
            a.y = f2bf(last ? silu_f(oy) : oy);
            *(ushort2*)&Ab[row][2 * l] = a;
        }
    }
    __syncthreads();

    if (!last) {
        f32x4 acc[2][2] = {{{0, 0, 0, 0}, {0, 0, 0, 0}}, {{0, 0, 0, 0}, {0, 0, 0, 0}}};
        gemm32(Ab, Wt, w * 32, acc);
        int c = w * 32 + m;
#pragma unroll
        for (int half = 0; half < 2; ++half)
#pragma unroll
            for (int r = 0; r < 4; ++r) {
                int row = half * 16 + q4 * 4 + r;
                u16* xr = xout + (size_t)(r0 + row) * HIDD;
                xr[c] = f2bf(acc[half][0][r]);
                xr[c + 16] = f2bf(acc[half][1][r]);
            }
    } else {
        f32x4 a0 = {0, 0, 0, 0}, a1 = {0, 0, 0, 0};
        int n0 = w * 16;
#pragma unroll
        for (int kc = 0; kc < 128; kc += 32) {
            short8x av0 = *(const short8x*)&Ab[m][kc + q8];
            short8x av1 = *(const short8x*)&Ab[16 + m][kc + q8];
            short8x bv = *(const short8x*)&Wt[n0 + m][kc + q8];
            a0 = __builtin_amdgcn_mfma_f32_16x16x32_bf16(av0, bv, a0, 0, 0, 0);
            a1 = __builtin_amdgcn_mfma_f32_16x16x32_bf16(av1, bv, a1, 0, 0, 0);
        }
        int c = n0 + m;
        float bv = rb1[c], wv = rw2[c];
        float tsum = 0.0f;
#pragma unroll
        for (int r = 0; r < 4; ++r) {
            tsum += silu_f(a0[r] + bv) * wv;
            tsum += silu_f(a1[r] + bv) * wv;
        }
#pragma unroll
        for (int mm = 32; mm; mm >>= 1) tsum += __shfl_xor(tsum, mm);
        if (l == 0) red[w] = tsum;
        __syncthreads();
        if (tid == 0) {
            float tot = red[0] + red[1] + red[2] + red[3] + (float)MROWS * rb2[0];
            atomicAdd(&out[r0 >> 7], tot);
        }
    }
}

extern "C" void kernel_launch(void* const* d_in, const int* in_sizes, int n_in,
                              void* d_out, int out_size, void* d_ws, size_t ws_size,
                              hipStream_t stream) {
    const int*   Z   = (const int*)d_in[0];
    const float* pos = (const float*)d_in[1];
    const int*   ei  = (const int*)d_in[2];
    const float* ew  = (const float*)d_in[3];
    const float* ew1 = (const float*)d_in[4];
    const float* eb1 = (const float*)d_in[5];
    const float* ew2 = (const float*)d_in[6];
    const float* eb2 = (const float*)d_in[7];
    const float* liw = (const float*)d_in[8];
    const float* nw1 = (const float*)d_in[9];
    const float* nb1 = (const float*)d_in[10];
    const float* nw2 = (const float*)d_in[11];
    const float* nb2 = (const float*)d_in[12];
    const float* lng = (const float*)d_in[13];
    const float* lnb = (const float*)d_in[14];
    const float* rw1 = (const float*)d_in[15];
    const float* rb1 = (const float*)d_in[16];
    const float* rw2 = (const float*)d_in[17];
    const float* rb2 = (const float*)d_in[18];
    float* out = (float*)d_out;

    float* h      = (float*)d_ws;                            // 4 MB
    u16*   xb0    = (u16*)(h + (size_t)BN * HIDD);           // 2 MB
    u16*   xb1    = xb0 + (size_t)BN * HIDD;                 // 2 MB
    u16*   aggb   = xb1 + (size_t)BN * HIDD;                 // 2 MB
    u16*   lutall = aggb + (size_t)BN * HIDD;                // 2 MB
    u16*   liwT   = lutall + (size_t)NBLK * TLUT * HIDD;     // 128 KB
    u16*   nw1T   = liwT + (size_t)NBLK * HIDD * HIDD;
    u16*   nw2T   = nw1T + (size_t)NBLK * HIDD * HIDD;
    u16*   ro1T   = nw2T + (size_t)NBLK * HIDD * HIDD;       // 16 KB
    int*   cnt    = (int*)(ro1T + 64 * HIDD);                // 32 KB
    int*   meta   = (int*)(cnt + BN);                        // 4 MB

    (void)hipMemsetAsync(cnt, 0, BN * sizeof(int), stream);
    k_setup<<<1920, 256, 0, stream>>>(Z, pos, ei, ew, ew1, eb1, ew2, eb2,
                                      liw, nw1, nw2, rw1,
                                      cnt, meta, lutall, h, xb0,
                                      liwT, nw1T, nw2T, ro1T, out, out_size);

    u16* xbuf[2] = {xb0, xb1};
    for (int i = 0; i < NBLK; ++i) {
        int last = (i == NBLK - 1);
        k_agg<<<BN / 4, 256, 0, stream>>>(cnt, meta,
                                          lutall + (size_t)i * TLUT * HIDD,
                                          xbuf[i & 1], aggb);
        k_mlp<<<BN / MROWS, 256, 0, stream>>>(
            aggb, h,
            nw1T + (size_t)i * HIDD * HIDD, nb1 + i * HIDD,
            nw2T + (size_t)i * HIDD * HIDD, nb2 + i * HIDD,
            lng + i * HIDD, lnb + i * HIDD,
            last ? ro1T : liwT + (size_t)(i + 1) * HIDD * HIDD,
            last ? (u16*)nullptr : xbuf[(i + 1) & 1],
            last, rb1, rw2, rb2, out);
    }
}

// Round 8
// 231.097 us; speedup vs baseline: 3.1252x; 1.2517x over previous
//
#include <hip/hip_runtime.h>

#define BN 8192
#define EE 262144
#define HIDD 128
#define NRBF 64
#define NBLK 4
#define TLUT 2048
#define CAP 128
#define MR 16
#define FR 8
#define RCUTF 6.0f
#define GAMMAF (10.0f / 36.0f)

typedef unsigned short u16;
typedef __attribute__((ext_vector_type(8))) short short8x;
typedef __attribute__((ext_vector_type(4))) float f32x4;

__device__ __forceinline__ float silu_f(float v) {
    return v / (1.0f + __expf(-v));
}
__device__ __forceinline__ float bf2f(u16 u) {
    return __uint_as_float(((unsigned)u) << 16);
}
__device__ __forceinline__ u16 f2bf(float f) {
    unsigned u = __float_as_uint(f);
    unsigned r = u + 0x7FFFu + ((u >> 16) & 1u);
    return (u16)(r >> 16);
}

// ---- prep: bf16-transpose weights to [n][k], zero cnt & out (R4-proven) -----
__global__ void k_prep(const float* __restrict__ liw, const float* __restrict__ nw1,
                       const float* __restrict__ nw2, const float* __restrict__ ro1,
                       u16* __restrict__ liwT, u16* __restrict__ nw1T,
                       u16* __restrict__ nw2T, u16* __restrict__ ro1T,
                       int* __restrict__ cnt, float* __restrict__ out, int out_n) {
    int id0 = blockIdx.x * 256 + threadIdx.x;
    for (int id = id0; id < 12 * 16384; id += 65536) {
        int which = id >> 14;
        int r = id & 16383;
        int n = r >> 7, k = r & 127;
        const float* src = which < 4 ? liw : (which < 8 ? nw1 : nw2);
        u16* dst = which < 4 ? liwT : (which < 8 ? nw1T : nw2T);
        int b = which & 3;
        dst[b * 16384 + n * 128 + k] = f2bf(src[(size_t)b * 16384 + k * 128 + n]);
    }
    if (id0 < 8192) {
        cnt[id0] = 0;
        int n = id0 >> 7, k = id0 & 127;
        ro1T[n * 128 + k] = f2bf(ro1[k * 64 + n]);
        if (id0 < out_n) out[id0] = 0.0f;
    }
}

// ---- edges: bucket by dst, pack (i0<<13 | src), nearest-LUT index -----------
__global__ void k_edges(const int* __restrict__ ei, const float* __restrict__ pos,
                        int* __restrict__ cnt, int* __restrict__ meta) {
    int e = blockIdx.x * 256 + threadIdx.x;
    int s = ei[e];
    int d = ei[EE + e];
    float dx = pos[s * 3 + 0] - pos[d * 3 + 0];
    float dy = pos[s * 3 + 1] - pos[d * 3 + 1];
    float dz = pos[s * 3 + 2] - pos[d * 3 + 2];
    float dist = fminf(sqrtf(dx * dx + dy * dy + dz * dz), RCUTF);
    int i0 = (int)(dist * ((TLUT - 1) / RCUTF) + 0.5f);
    i0 = i0 > TLUT - 1 ? TLUT - 1 : i0;
    int p = atomicAdd(&cnt[d], 1);
    if (p < CAP) meta[(size_t)d * CAP + p] = (i0 << 13) | s;
}

// ---- filter LUT for all 4 nets (RBF inline, VALU GEMM). grid=256 ------------
__global__ __launch_bounds__(256) void k_lutall(const float* __restrict__ W1a,
                                                const float* __restrict__ b1a,
                                                const float* __restrict__ W2a,
                                                const float* __restrict__ b2a,
                                                u16* __restrict__ lutall) {
    __shared__ float As[32 * 33];
    __shared__ float Ws[32 * 128];
    __shared__ float T2[32 * 128];
    int net = blockIdx.x >> 6;
    int r0l = (blockIdx.x & 63) * 32;
    const float* W1 = W1a + (size_t)net * NRBF * HIDD;
    const float* b1 = b1a + net * HIDD;
    const float* W2 = W2a + (size_t)net * HIDD * HIDD;
    const float* b2 = b2a + net * HIDD;
    u16* lutp = lutall + (size_t)net * TLUT * HIDD;
    int tid = threadIdx.x;
    int tx = tid & 31, ty = tid >> 5;
    int c0 = tx * 4, rr = ty * 4;
    float acc[4][4] = {};
    for (int kc = 0; kc < NRBF; kc += 32) {
        int lr = tid >> 3, lc = (tid & 7) * 4;
        float dt = (r0l + lr) * (RCUTF / (TLUT - 1));
#pragma unroll
        for (int j = 0; j < 4; ++j) {
            float c = (kc + lc + j) * (RCUTF / 63.0f);
            float u = dt - c;
            As[lr * 33 + lc + j] = __expf(-GAMMAF * u * u);
        }
#pragma unroll
        for (int j = 0; j < 4; ++j) {
            int idx = tid + j * 256;
            int wr = idx >> 5, wc = (idx & 31) * 4;
            *(float4*)&Ws[wr * 128 + wc] =
                *(const float4*)&W1[(size_t)(kc + wr) * HIDD + wc];
        }
        __syncthreads();
#pragma unroll 8
        for (int k = 0; k < 32; ++k) {
            float4 wv = *(float4*)&Ws[k * 128 + c0];
            float a0 = As[(rr + 0) * 33 + k];
            float a1 = As[(rr + 1) * 33 + k];
            float a2 = As[(rr + 2) * 33 + k];
            float a3 = As[(rr + 3) * 33 + k];
            acc[0][0] += a0 * wv.x; acc[0][1] += a0 * wv.y; acc[0][2] += a0 * wv.z; acc[0][3] += a0 * wv.w;
            acc[1][0] += a1 * wv.x; acc[1][1] += a1 * wv.y; acc[1][2] += a1 * wv.z; acc[1][3] += a1 * wv.w;
            acc[2][0] += a2 * wv.x; acc[2][1] += a2 * wv.y; acc[2][2] += a2 * wv.z; acc[2][3] += a2 * wv.w;
            acc[3][0] += a3 * wv.x; acc[3][1] += a3 * wv.y; acc[3][2] += a3 * wv.z; acc[3][3] += a3 * wv.w;
        }
        __syncthreads();
    }
#pragma unroll
    for (int i = 0; i < 4; ++i)
#pragma unroll
        for (int j = 0; j < 4; ++j)
            T2[(rr + i) * 128 + c0 + j] = silu_f(acc[i][j] + b1[c0 + j]);
    float acc2[4][4] = {};
    __syncthreads();
    for (int kc = 0; kc < HIDD; kc += 32) {
#pragma unroll
        for (int j = 0; j < 4; ++j) {
            int idx = tid + j * 256;
            int wr = idx >> 5, wc = (idx & 31) * 4;
            *(float4*)&Ws[wr * 128 + wc] =
                *(const float4*)&W2[(size_t)(kc + wr) * HIDD + wc];
        }
        __syncthreads();
#pragma unroll 8
        for (int k = 0; k < 32; ++k) {
            float4 wv = *(float4*)&Ws[k * 128 + c0];
            float a0 = T2[(rr + 0) * 128 + kc + k];
            float a1 = T2[(rr + 1) * 128 + kc + k];
            float a2 = T2[(rr + 2) * 128 + kc + k];
            float a3 = T2[(rr + 3) * 128 + kc + k];
            acc2[0][0] += a0 * wv.x; acc2[0][1] += a0 * wv.y; acc2[0][2] += a0 * wv.z; acc2[0][3] += a0 * wv.w;
            acc2[1][0] += a1 * wv.x; acc2[1][1] += a1 * wv.y; acc2[1][2] += a1 * wv.z; acc2[1][3] += a1 * wv.w;
            acc2[2][0] += a2 * wv.x; acc2[2][1] += a2 * wv.y; acc2[2][2] += a2 * wv.z; acc2[2][3] += a2 * wv.w;
            acc2[3][0] += a3 * wv.x; acc2[3][1] += a3 * wv.y; acc2[3][2] += a3 * wv.z; acc2[3][3] += a3 * wv.w;
        }
        __syncthreads();
    }
#pragma unroll
    for (int i = 0; i < 4; ++i) {
        int t = r0l + rr + i;
        ushort4 o;
        o.x = f2bf(acc2[i][0] + b2[c0 + 0]);
        o.y = f2bf(acc2[i][1] + b2[c0 + 1]);
        o.z = f2bf(acc2[i][2] + b2[c0 + 2]);
        o.w = f2bf(acc2[i][3] + b2[c0 + 3]);
        *(ushort4*)&lutp[(size_t)t * HIDD + c0] = o;
    }
}

// ---- embed + x0 = h @ liwT[0] (R4-proven) -----------------------------------
__global__ __launch_bounds__(256, 2) void k_embedx(const int* __restrict__ Z,
                                                   const float* __restrict__ ew,
                                                   const u16* __restrict__ liwT0,
                                                   float* __restrict__ h,
                                                   u16* __restrict__ xb) {
    __shared__ u16 Wt[128][136];
    __shared__ u16 Ab[MR][136];
    int tid = threadIdx.x;
    int r0 = blockIdx.x * MR;
    {
        int row = tid >> 4, c8 = (tid & 15) * 8;
        int z = Z[r0 + row];
        const float* er = ew + (size_t)z * HIDD + c8;
        float* hr = h + (size_t)(r0 + row) * HIDD + c8;
        float4 v0 = *(const float4*)er;
        float4 v1 = *(const float4*)(er + 4);
        *(float4*)hr = v0;
        *(float4*)(hr + 4) = v1;
        ushort4 a0, a1;
        a0.x = f2bf(v0.x); a0.y = f2bf(v0.y); a0.z = f2bf(v0.z); a0.w = f2bf(v0.w);
        a1.x = f2bf(v1.x); a1.y = f2bf(v1.y); a1.z = f2bf(v1.z); a1.w = f2bf(v1.w);
        *(ushort4*)&Ab[row][c8] = a0;
        *(ushort4*)&Ab[row][c8 + 4] = a1;
    }
    for (int idx = tid; idx < 2048; idx += 256) {
        int r = idx >> 4, c = (idx & 15) * 8;
        *(float4*)&Wt[r][c] = *(const float4*)&liwT0[r * HIDD + c];
    }
    __syncthreads();
    int w = tid >> 6, l = tid & 63;
    int m = l & 15, q4 = l >> 4, q8 = q4 * 8;
    f32x4 a0 = {0, 0, 0, 0}, a1 = {0, 0, 0, 0};
#pragma unroll
    for (int kc = 0; kc < 128; kc += 32) {
        short8x av = *(const short8x*)&Ab[m][kc + q8];
        short8x b0 = *(const short8x*)&Wt[w * 32 + m][kc + q8];
        short8x b1 = *(const short8x*)&Wt[w * 32 + 16 + m][kc + q8];
        a0 = __builtin_amdgcn_mfma_f32_16x16x32_bf16(av, b0, a0, 0, 0, 0);
        a1 = __builtin_amdgcn_mfma_f32_16x16x32_bf16(av, b1, a1, 0, 0, 0);
    }
    int c = w * 32 + m;
#pragma unroll
    for (int r = 0; r < 4; ++r) {
        int row = q4 * 4 + r;
        u16* xr = xb + (size_t)(r0 + row) * HIDD;
        xr[c] = f2bf(a0[r]);
        xr[c + 16] = f2bf(a1[r]);
    }
}

// ---- fused gather + node MLP + LN + (next-x | readout) ----------------------
// 512 thr (8 waves), FR=8 rows/block, 1024 blocks. 1 dst per wave for gather.
// Flat LDS: Ab @0 (8x136), Tb @1088 (8x136), Wt @2176 (128x136).
// MFMA A-operand reads rows 0..15: rows 8..15 over-read into the next region
// (in-bounds by construction, values don't affect rows 0..7 of C).
__global__ __launch_bounds__(512, 6) void k_fiter(
    const int* __restrict__ cnt, const int* __restrict__ meta,
    const u16* __restrict__ lut, const u16* __restrict__ xin,
    float* __restrict__ h,
    const u16* __restrict__ w1t, const float* __restrict__ b1,
    const u16* __restrict__ w2t, const float* __restrict__ b2,
    const float* __restrict__ g, const float* __restrict__ bb,
    const u16* __restrict__ w3t, u16* __restrict__ xout, int last,
    const float* __restrict__ rb1, const float* __restrict__ rw2,
    const float* __restrict__ rb2, float* __restrict__ out) {
    __shared__ u16 SH[2176 + 128 * 136];     // Ab | Tb | Wt
    __shared__ float RED[152];               // S[64] Q[64] MU[8] RS[8] ROUT[8]
    int tid = threadIdx.x;
    int w = tid >> 6, l = tid & 63;
    int m = l & 15, q4 = l >> 4, q8 = q4 * 8;
    int r0 = blockIdx.x * FR;
    u16* Ab = SH;
    u16* Tb = SH + 1088;
    u16* Wt = SH + 2176;

    // --- gather: wave w owns dst r0+w ------------------------------------
    {
        int dst = r0 + w;
        int n = cnt[dst];
        n = n > CAP ? CAP : n;
        const int* mp = meta + (size_t)dst * CAP;
        int nm1 = n > 0 ? n - 1 : 0;
        int mA = mp[l < nm1 ? l : nm1];
        int mB = mp[64 + l < nm1 ? 64 + l : nm1];
        float ax = 0.0f, ay = 0.0f;
#pragma unroll 4
        for (int t = 0; t < n; ++t) {
            int md = __shfl(t < 64 ? mA : mB, t & 63);
            int s = md & 8191;
            int i0 = md >> 13;
            ushort2 lv = *(const ushort2*)&lut[((size_t)i0 << 7) + 2 * l];
            ushort2 xv = *(const ushort2*)&xin[((size_t)s << 7) + 2 * l];
            ax = fmaf(bf2f(lv.x), bf2f(xv.x), ax);
            ay = fmaf(bf2f(lv.y), bf2f(xv.y), ay);
        }
        ushort2 o;
        o.x = f2bf(ax);
        o.y = f2bf(ay);
        *(ushort2*)&Ab[w * 136 + 2 * l] = o;
    }
    // stage W1 (all 512 threads)
    for (int idx = tid; idx < 2048; idx += 512) {
        int r = idx >> 4, c = (idx & 15) * 8;
        *(float4*)&Wt[r * 136 + c] = *(const float4*)&w1t[r * HIDD + c];
    }
    __syncthreads();

    // --- GEMM1: wave w -> cols w*16..+15, rows 0..7 real -----------------
    int col = w * 16 + m;
    f32x4 ac1 = {0, 0, 0, 0};
#pragma unroll
    for (int kc = 0; kc < 128; kc += 32) {
        short8x av = *(const short8x*)&Ab[m * 136 + kc + q8];
        short8x bv = *(const short8x*)&Wt[(w * 16 + m) * 136 + kc + q8];
        ac1 = __builtin_amdgcn_mfma_f32_16x16x32_bf16(av, bv, ac1, 0, 0, 0);
    }
    __syncthreads();   // Wt/Ab reads done
    {
        float bv = b1[col];
        if (q4 < 2) {
#pragma unroll
            for (int r = 0; r < 4; ++r)
                Tb[(q4 * 4 + r) * 136 + col] = f2bf(silu_f(ac1[r] + bv));
        }
    }
    for (int idx = tid; idx < 2048; idx += 512) {
        int r = idx >> 4, c = (idx & 15) * 8;
        *(float4*)&Wt[r * 136 + c] = *(const float4*)&w2t[r * HIDD + c];
    }
    __syncthreads();

    // --- GEMM2 + bias + residual -----------------------------------------
    f32x4 ac2 = {0, 0, 0, 0};
#pragma unroll
    for (int kc = 0; kc < 128; kc += 32) {
        short8x av = *(const short8x*)&Tb[m * 136 + kc + q8];
        short8x bv = *(const short8x*)&Wt[(w * 16 + m) * 136 + kc + q8];
        ac2 = __builtin_amdgcn_mfma_f32_16x16x32_bf16(av, bv, ac2, 0, 0, 0);
    }
    float v[4], sS = 0.0f, sQ = 0.0f;
    if (q4 < 2) {
        float bv = b2[col];
#pragma unroll
        for (int r = 0; r < 4; ++r) {
            int row = q4 * 4 + r;
            v[r] = ac2[r] + bv + h[(size_t)(r0 + row) * HIDD + col];
        }
    }
    __syncthreads();   // Wt/Tb reads done

    // --- LN partials (16 cols per wave) + stage W3 -----------------------
    if (q4 < 2) {
        // reduce across the 16-lane col group, per row
#pragma unroll
        for (int r = 0; r < 4; ++r) {
            float s = v[r], q = v[r] * v[r];
#pragma unroll
            for (int mm = 1; mm < 16; mm <<= 1) {
                s += __shfl_xor(s, mm);
                q += __shfl_xor(q, mm);
            }
            if (m == 0) {
                RED[w * 8 + q4 * 4 + r] = s;
                RED[64 + w * 8 + q4 * 4 + r] = q;
            }
        }
    }
    {
        int rows3 = last ? 64 : 128;
        for (int idx = tid; idx < rows3 * 16; idx += 512) {
            int r = idx >> 4, c = (idx & 15) * 8;
            *(float4*)&Wt[r * 136 + c] = *(const float4*)&w3t[r * HIDD + c];
        }
    }
    __syncthreads();
    if (tid < 8) {
        float s = 0.0f, q = 0.0f;
#pragma unroll
        for (int ww = 0; ww < 8; ++ww) {
            s += RED[ww * 8 + tid];
            q += RED[64 + ww * 8 + tid];
        }
        float mu = s * (1.0f / 128.0f);
        float var = q * (1.0f / 128.0f) - mu * mu;
        RED[128 + tid] = mu;
        RED[136 + tid] = rsqrtf(var + 1e-5f);
    }
    __syncthreads();
    if (q4 < 2) {
        float gv = g[col], bbv = bb[col];
#pragma unroll
        for (int r = 0; r < 4; ++r) {
            int row = q4 * 4 + r;
            float mu = RED[128 + row], rs = RED[136 + row];
            float o = (v[r] - mu) * rs * gv + bbv;
            if (!last) h[(size_t)(r0 + row) * HIDD + col] = o;
            Ab[row * 136 + col] = f2bf(last ? silu_f(o) : o);
        }
    }
    __syncthreads();

    // --- GEMM3: next x  OR  readout --------------------------------------
    if (!last) {
        f32x4 ac3 = {0, 0, 0, 0};
#pragma unroll
        for (int kc = 0; kc < 128; kc += 32) {
            short8x av = *(const short8x*)&Ab[m * 136 + kc + q8];
            short8x bv = *(const short8x*)&Wt[(w * 16 + m) * 136 + kc + q8];
            ac3 = __builtin_amdgcn_mfma_f32_16x16x32_bf16(av, bv, ac3, 0, 0, 0);
        }
        if (q4 < 2) {
#pragma unroll
            for (int r = 0; r < 4; ++r) {
                int row = q4 * 4 + r;
                xout[(size_t)(r0 + row) * HIDD + col] = f2bf(ac3[r]);
            }
        }
    } else {
        float tsum = 0.0f;
        if (w < 4) {
            f32x4 ac3 = {0, 0, 0, 0};
#pragma unroll
            for (int kc = 0; kc < 128; kc += 32) {
                short8x av = *(const short8x*)&Ab[m * 136 + kc + q8];
                short8x bv = *(const short8x*)&Wt[(w * 16 + m) * 136 + kc + q8];
                ac3 = __builtin_amdgcn_mfma_f32_16x16x32_bf16(av, bv, ac3, 0, 0, 0);
            }
            if (q4 < 2) {
                float bv = rb1[col], wv = rw2[col];
#pragma unroll
                for (int r = 0; r < 4; ++r) tsum += silu_f(ac3[r] + bv) * wv;
            }
#pragma unroll
            for (int mm = 1; mm < 64; mm <<= 1) tsum += __shfl_xor(tsum, mm);
            if (l == 0) RED[144 + w] = tsum;
        }
        __syncthreads();
        if (tid == 0) {
            float tot = RED[144] + RED[145] + RED[146] + RED[147] +
                        (float)FR * rb2[0];
            atomicAdd(&out[blockIdx.x >> 4], tot);
        }
    }
}

extern "C" void kernel_launch(void* const* d_in, const int* in_sizes, int n_in,
                              void* d_out, int out_size, void* d_ws, size_t ws_size,
                              hipStream_t stream) {
    const int*   Z   = (const int*)d_in[0];
    const float* pos = (const float*)d_in[1];
    const int*   ei  = (const int*)d_in[2];
    const float* ew  = (const float*)d_in[3];
    const float* ew1 = (const float*)d_in[4];
    const float* eb1 = (const float*)d_in[5];
    const float* ew2 = (const float*)d_in[6];
    const float* eb2 = (const float*)d_in[7];
    const float* liw = (const float*)d_in[8];
    const float* nw1 = (const float*)d_in[9];
    const float* nb1 = (const float*)d_in[10];
    const float* nw2 = (const float*)d_in[11];
    const float* nb2 = (const float*)d_in[12];
    const float* lng = (const float*)d_in[13];
    const float* lnb = (const float*)d_in[14];
    const float* rw1 = (const float*)d_in[15];
    const float* rb1 = (const float*)d_in[16];
    const float* rw2 = (const float*)d_in[17];
    const float* rb2 = (const float*)d_in[18];
    float* out = (float*)d_out;

    float* h      = (float*)d_ws;                            // 4 MB
    u16*   xb0    = (u16*)(h + (size_t)BN * HIDD);           // 2 MB
    u16*   xb1    = xb0 + (size_t)BN * HIDD;                 // 2 MB
    u16*   lutall = xb1 + (size_t)BN * HIDD;                 // 2 MB
    u16*   liwT   = lutall + (size_t)NBLK * TLUT * HIDD;     // 128 KB
    u16*   nw1T   = liwT + (size_t)NBLK * HIDD * HIDD;
    u16*   nw2T   = nw1T + (size_t)NBLK * HIDD * HIDD;
    u16*   ro1T   = nw2T + (size_t)NBLK * HIDD * HIDD;       // 16 KB
    int*   cnt    = (int*)(ro1T + 64 * HIDD);                // 32 KB
    int*   meta   = (int*)(cnt + BN);                        // 4 MB

    k_prep<<<256, 256, 0, stream>>>(liw, nw1, nw2, rw1, liwT, nw1T, nw2T, ro1T,
                                    cnt, out, out_size);
    k_edges<<<EE / 256, 256, 0, stream>>>(ei, pos, cnt, meta);
    k_lutall<<<NBLK * (TLUT / 32), 256, 0, stream>>>(ew1, eb1, ew2, eb2, lutall);
    k_embedx<<<BN / MR, 256, 0, stream>>>(Z, ew, liwT, h, xb0);

    u16* xbuf[2] = {xb0, xb1};
    for (int i = 0; i < NBLK; ++i) {
        int last = (i == NBLK - 1);
        k_fiter<<<BN / FR, 512, 0, stream>>>(
            cnt, meta, lutall + (size_t)i * TLUT * HIDD, xbuf[i & 1], h,
            nw1T + (size_t)i * HIDD * HIDD, nb1 + i * HIDD,
            nw2T + (size_t)i * HIDD * HIDD, nb2 + i * HIDD,
            lng + i * HIDD, lnb + i * HIDD,
            last ? ro1T : liwT + (size_t)(i + 1) * HIDD * HIDD,
            last ? (u16*)nullptr : xbuf[(i + 1) & 1],
            last, rb1, rw2, rb2, out);
    }
}

// Round 9
// 210.234 us; speedup vs baseline: 3.4353x; 1.0992x over previous
//
#include <hip/hip_runtime.h>

#define BN 8192
#define EE 262144
#define HIDD 128
#define NRBF 64
#define NBLK 4
#define TLUT 2048
#define CAP 128
#define MR 16
#define FR 8
#define RCUTF 6.0f
#define GAMMAF (10.0f / 36.0f)

typedef unsigned short u16;
typedef __attribute__((ext_vector_type(8))) short short8x;
typedef __attribute__((ext_vector_type(8))) unsigned short u16x8;
typedef __attribute__((ext_vector_type(4))) float f32x4;

__device__ __forceinline__ float silu_f(float v) {
    return v / (1.0f + __expf(-v));
}
__device__ __forceinline__ float bf2f(u16 u) {
    return __uint_as_float(((unsigned)u) << 16);
}
__device__ __forceinline__ u16 f2bf(float f) {
    unsigned u = __float_as_uint(f);
    unsigned r = u + 0x7FFFu + ((u >> 16) & 1u);
    return (u16)(r >> 16);
}

// ---- k_pe: weight transposes + edge bucketing (all LDS-free) ----------------
// blocks 0..1023: edges; 1024..1791: transposes; 1792..1823: ro1T + out zero.
// cnt must be zeroed by a preceding memset.
__global__ void k_pe(const int* __restrict__ ei, const float* __restrict__ pos,
                     const float* __restrict__ liw, const float* __restrict__ nw1,
                     const float* __restrict__ nw2, const float* __restrict__ ro1,
                     int* __restrict__ cnt, int* __restrict__ meta,
                     u16* __restrict__ liwT, u16* __restrict__ nw1T,
                     u16* __restrict__ nw2T, u16* __restrict__ ro1T,
                     float* __restrict__ out, int out_n) {
    int tid = threadIdx.x, blk = blockIdx.x;
    if (blk < 1024) {
        int e = blk * 256 + tid;
        int s = ei[e];
        int d = ei[EE + e];
        float dx = pos[s * 3 + 0] - pos[d * 3 + 0];
        float dy = pos[s * 3 + 1] - pos[d * 3 + 1];
        float dz = pos[s * 3 + 2] - pos[d * 3 + 2];
        float dist = fminf(sqrtf(dx * dx + dy * dy + dz * dz), RCUTF);
        int i0 = (int)(dist * ((TLUT - 1) / RCUTF) + 0.5f);
        i0 = i0 > TLUT - 1 ? TLUT - 1 : i0;
        int p = atomicAdd(&cnt[d], 1);
        if (p < CAP) meta[(size_t)d * CAP + p] = (i0 << 13) | s;
    } else if (blk < 1792) {
        int id = (blk - 1024) * 256 + tid;     // [0, 196608) = 12*16384
        int which = id >> 14;
        int r = id & 16383;
        int n = r >> 7, k = r & 127;
        const float* src = which < 4 ? liw : (which < 8 ? nw1 : nw2);
        u16* dst = which < 4 ? liwT : (which < 8 ? nw1T : nw2T);
        int b = which & 3;
        dst[b * 16384 + n * 128 + k] = f2bf(src[(size_t)b * 16384 + k * 128 + n]);
    } else {
        int id = (blk - 1792) * 256 + tid;     // [0, 8192)
        int n = id >> 7, k = id & 127;
        ro1T[n * 128 + k] = f2bf(ro1[(size_t)k * 64 + n]);
        if (blk == 1792 && tid < out_n) out[tid] = 0.0f;
    }
}

// ---- k_le: filter-LUT MLP (blocks 0..255) | embed + x0 (blocks 256..767) ----
__global__ __launch_bounds__(256, 2) void k_le(
    const float* __restrict__ W1a, const float* __restrict__ b1a,
    const float* __restrict__ W2a, const float* __restrict__ b2a,
    u16* __restrict__ lutall,
    const int* __restrict__ Z, const float* __restrict__ ew,
    const u16* __restrict__ liwT0, float* __restrict__ h,
    u16* __restrict__ xb) {
    __shared__ union {
        struct { float As[32 * 33]; float Ws[32 * 128]; float T2[32 * 128]; } lu;
        struct { u16 Wt[128][136]; u16 Ab[MR][136]; } ex;
    } S;
    int tid = threadIdx.x, blk = blockIdx.x;
    if (blk < 256) {
        int net = blk >> 6;
        int r0l = (blk & 63) * 32;
        const float* W1 = W1a + (size_t)net * NRBF * HIDD;
        const float* b1 = b1a + net * HIDD;
        const float* W2 = W2a + (size_t)net * HIDD * HIDD;
        const float* b2 = b2a + net * HIDD;
        u16* lutp = lutall + (size_t)net * TLUT * HIDD;
        int tx = tid & 31, ty = tid >> 5;
        int c0 = tx * 4, rr = ty * 4;
        float acc[4][4] = {};
        for (int kc = 0; kc < NRBF; kc += 32) {
            int lr = tid >> 3, lc = (tid & 7) * 4;
            float dt = (r0l + lr) * (RCUTF / (TLUT - 1));
#pragma unroll
            for (int j = 0; j < 4; ++j) {
                float c = (kc + lc + j) * (RCUTF / 63.0f);
                float u = dt - c;
                S.lu.As[lr * 33 + lc + j] = __expf(-GAMMAF * u * u);
            }
#pragma unroll
            for (int j = 0; j < 4; ++j) {
                int idx = tid + j * 256;
                int wr = idx >> 5, wc = (idx & 31) * 4;
                *(float4*)&S.lu.Ws[wr * 128 + wc] =
                    *(const float4*)&W1[(size_t)(kc + wr) * HIDD + wc];
            }
            __syncthreads();
#pragma unroll 8
            for (int k = 0; k < 32; ++k) {
                float4 wv = *(float4*)&S.lu.Ws[k * 128 + c0];
                float a0 = S.lu.As[(rr + 0) * 33 + k];
                float a1 = S.lu.As[(rr + 1) * 33 + k];
                float a2 = S.lu.As[(rr + 2) * 33 + k];
                float a3 = S.lu.As[(rr + 3) * 33 + k];
                acc[0][0] += a0 * wv.x; acc[0][1] += a0 * wv.y; acc[0][2] += a0 * wv.z; acc[0][3] += a0 * wv.w;
                acc[1][0] += a1 * wv.x; acc[1][1] += a1 * wv.y; acc[1][2] += a1 * wv.z; acc[1][3] += a1 * wv.w;
                acc[2][0] += a2 * wv.x; acc[2][1] += a2 * wv.y; acc[2][2] += a2 * wv.z; acc[2][3] += a2 * wv.w;
                acc[3][0] += a3 * wv.x; acc[3][1] += a3 * wv.y; acc[3][2] += a3 * wv.z; acc[3][3] += a3 * wv.w;
            }
            __syncthreads();
        }
#pragma unroll
        for (int i = 0; i < 4; ++i)
#pragma unroll
            for (int j = 0; j < 4; ++j)
                S.lu.T2[(rr + i) * 128 + c0 + j] = silu_f(acc[i][j] + b1[c0 + j]);
        float acc2[4][4] = {};
        __syncthreads();
        for (int kc = 0; kc < HIDD; kc += 32) {
#pragma unroll
            for (int j = 0; j < 4; ++j) {
                int idx = tid + j * 256;
                int wr = idx >> 5, wc = (idx & 31) * 4;
                *(float4*)&S.lu.Ws[wr * 128 + wc] =
                    *(const float4*)&W2[(size_t)(kc + wr) * HIDD + wc];
            }
            __syncthreads();
#pragma unroll 8
            for (int k = 0; k < 32; ++k) {
                float4 wv = *(float4*)&S.lu.Ws[k * 128 + c0];
                float a0 = S.lu.T2[(rr + 0) * 128 + kc + k];
                float a1 = S.lu.T2[(rr + 1) * 128 + kc + k];
                float a2 = S.lu.T2[(rr + 2) * 128 + kc + k];
                float a3 = S.lu.T2[(rr + 3) * 128 + kc + k];
                acc2[0][0] += a0 * wv.x; acc2[0][1] += a0 * wv.y; acc2[0][2] += a0 * wv.z; acc2[0][3] += a0 * wv.w;
                acc2[1][0] += a1 * wv.x; acc2[1][1] += a1 * wv.y; acc2[1][2] += a1 * wv.z; acc2[1][3] += a1 * wv.w;
                acc2[2][0] += a2 * wv.x; acc2[2][1] += a2 * wv.y; acc2[2][2] += a2 * wv.z; acc2[2][3] += a2 * wv.w;
                acc2[3][0] += a3 * wv.x; acc2[3][1] += a3 * wv.y; acc2[3][2] += a3 * wv.z; acc2[3][3] += a3 * wv.w;
            }
            __syncthreads();
        }
#pragma unroll
        for (int i = 0; i < 4; ++i) {
            int t = r0l + rr + i;
            ushort4 o;
            o.x = f2bf(acc2[i][0] + b2[c0 + 0]);
            o.y = f2bf(acc2[i][1] + b2[c0 + 1]);
            o.z = f2bf(acc2[i][2] + b2[c0 + 2]);
            o.w = f2bf(acc2[i][3] + b2[c0 + 3]);
            *(ushort4*)&lutp[(size_t)t * HIDD + c0] = o;
        }
    } else {
        int r0 = (blk - 256) * MR;
        {
            int row = tid >> 4, c8 = (tid & 15) * 8;
            int z = Z[r0 + row];
            const float* er = ew + (size_t)z * HIDD + c8;
            float* hr = h + (size_t)(r0 + row) * HIDD + c8;
            float4 v0 = *(const float4*)er;
            float4 v1 = *(const float4*)(er + 4);
            *(float4*)hr = v0;
            *(float4*)(hr + 4) = v1;
            ushort4 a0, a1;
            a0.x = f2bf(v0.x); a0.y = f2bf(v0.y); a0.z = f2bf(v0.z); a0.w = f2bf(v0.w);
            a1.x = f2bf(v1.x); a1.y = f2bf(v1.y); a1.z = f2bf(v1.z); a1.w = f2bf(v1.w);
            *(ushort4*)&S.ex.Ab[row][c8] = a0;
            *(ushort4*)&S.ex.Ab[row][c8 + 4] = a1;
        }
        for (int idx = tid; idx < 2048; idx += 256) {
            int r = idx >> 4, c = (idx & 15) * 8;
            *(float4*)&S.ex.Wt[r][c] = *(const float4*)&liwT0[r * HIDD + c];
        }
        __syncthreads();
        int w = tid >> 6, l = tid & 63;
        int m = l & 15, q4 = l >> 4, q8 = q4 * 8;
        f32x4 a0 = {0, 0, 0, 0}, a1 = {0, 0, 0, 0};
#pragma unroll
        for (int kc = 0; kc < 128; kc += 32) {
            short8x av = *(const short8x*)&S.ex.Ab[m][kc + q8];
            short8x b0 = *(const short8x*)&S.ex.Wt[w * 32 + m][kc + q8];
            short8x b1 = *(const short8x*)&S.ex.Wt[w * 32 + 16 + m][kc + q8];
            a0 = __builtin_amdgcn_mfma_f32_16x16x32_bf16(av, b0, a0, 0, 0, 0);
            a1 = __builtin_amdgcn_mfma_f32_16x16x32_bf16(av, b1, a1, 0, 0, 0);
        }
        int c = w * 32 + m;
#pragma unroll
        for (int r = 0; r < 4; ++r) {
            int row = q4 * 4 + r;
            u16* xr = xb + (size_t)(r0 + row) * HIDD;
            xr[c] = f2bf(a0[r]);
            xr[c + 16] = f2bf(a1[r]);
        }
    }
}

// ---- fused gather + node MLP + LN + (next-x | readout) ----------------------
// 512 thr (8 waves), FR=8 rows/block, 1024 blocks. Wave w owns dst r0+w.
// Gather: 4 edges/wave-iter, 16 lanes/row, 16B loads; quarter-reduce at end.
__global__ __launch_bounds__(512, 4) void k_fiter(
    const int* __restrict__ cnt, const int* __restrict__ meta,
    const u16* __restrict__ lut, const u16* __restrict__ xin,
    float* __restrict__ h,
    const u16* __restrict__ w1t, const float* __restrict__ b1,
    const u16* __restrict__ w2t, const float* __restrict__ b2,
    const float* __restrict__ g, const float* __restrict__ bb,
    const u16* __restrict__ w3t, u16* __restrict__ xout, int last,
    const float* __restrict__ rb1, const float* __restrict__ rw2,
    const float* __restrict__ rb2, float* __restrict__ out) {
    __shared__ u16 SH[2176 + 128 * 136];     // Ab(8x136) | Tb(8x136) | Wt(128x136)
    __shared__ float RED[152];               // S[64] Q[64] MU[8] RS[8] ROUT[8]
    int tid = threadIdx.x;
    int w = tid >> 6, l = tid & 63;
    int m = l & 15, q4 = l >> 4, q8 = q4 * 8;
    int r0 = blockIdx.x * FR;
    u16* Ab = SH;
    u16* Tb = SH + 1088;
    u16* Wt = SH + 2176;

    // --- gather: wave w owns dst r0+w; lane = (quarter q4, feat-group m) -----
    {
        int dst = r0 + w;
        int n = cnt[dst];
        n = n > CAP ? CAP : n;
        const int* mp = meta + (size_t)dst * CAP;
        int nm1 = n > 0 ? n - 1 : 0;
        int mA = mp[l < nm1 ? l : nm1];
        int mB = mp[64 + l < nm1 ? 64 + l : nm1];
        float ax[8] = {};
        int tmax = (n + 3) >> 2;
#pragma unroll 2
        for (int t = 0; t < tmax; ++t) {
            int e4 = t * 4 + q4;
            int md = __shfl(e4 < 64 ? mA : mB, e4 & 63);
            if (e4 < n) {
                int s = md & 8191;
                int i0 = md >> 13;
                u16x8 lv = *(const u16x8*)&lut[((size_t)i0 << 7) + 8 * m];
                u16x8 xv = *(const u16x8*)&xin[((size_t)s << 7) + 8 * m];
#pragma unroll
                for (int j = 0; j < 8; ++j)
                    ax[j] = fmaf(bf2f(lv[j]), bf2f(xv[j]), ax[j]);
            }
        }
#pragma unroll
        for (int j = 0; j < 8; ++j) {
            ax[j] += __shfl_xor(ax[j], 16);
            ax[j] += __shfl_xor(ax[j], 32);
        }
        if (q4 == 0) {
            u16x8 o;
#pragma unroll
            for (int j = 0; j < 8; ++j) o[j] = f2bf(ax[j]);
            *(u16x8*)&Ab[w * 136 + 8 * m] = o;
        }
    }
    for (int idx = tid; idx < 2048; idx += 512) {
        int r = idx >> 4, c = (idx & 15) * 8;
        *(float4*)&Wt[r * 136 + c] = *(const float4*)&w1t[r * HIDD + c];
    }
    __syncthreads();

    // --- GEMM1: wave w -> cols w*16..+15 (rows 0..7 real) --------------------
    int col = w * 16 + m;
    f32x4 ac1 = {0, 0, 0, 0};
#pragma unroll
    for (int kc = 0; kc < 128; kc += 32) {
        short8x av = *(const short8x*)&Ab[m * 136 + kc + q8];
        short8x bv = *(const short8x*)&Wt[(w * 16 + m) * 136 + kc + q8];
        ac1 = __builtin_amdgcn_mfma_f32_16x16x32_bf16(av, bv, ac1, 0, 0, 0);
    }
    __syncthreads();
    {
        float bv = b1[col];
        if (q4 < 2) {
#pragma unroll
            for (int r = 0; r < 4; ++r)
                Tb[(q4 * 4 + r) * 136 + col] = f2bf(silu_f(ac1[r] + bv));
        }
    }
    for (int idx = tid; idx < 2048; idx += 512) {
        int r = idx >> 4, c = (idx & 15) * 8;
        *(float4*)&Wt[r * 136 + c] = *(const float4*)&w2t[r * HIDD + c];
    }
    __syncthreads();

    // --- GEMM2 + bias + residual ---------------------------------------------
    f32x4 ac2 = {0, 0, 0, 0};
#pragma unroll
    for (int kc = 0; kc < 128; kc += 32) {
        short8x av = *(const short8x*)&Tb[m * 136 + kc + q8];
        short8x bv = *(const short8x*)&Wt[(w * 16 + m) * 136 + kc + q8];
        ac2 = __builtin_amdgcn_mfma_f32_16x16x32_bf16(av, bv, ac2, 0, 0, 0);
    }
    float v[4];
    if (q4 < 2) {
        float bv = b2[col];
#pragma unroll
        for (int r = 0; r < 4; ++r) {
            int row = q4 * 4 + r;
            v[r] = ac2[r] + bv + h[(size_t)(r0 + row) * HIDD + col];
        }
    }
    __syncthreads();

    // --- LN partials + stage W3 ----------------------------------------------
    if (q4 < 2) {
#pragma unroll
        for (int r = 0; r < 4; ++r) {
            float s = v[r], q = v[r] * v[r];
#pragma unroll
            for (int mm = 1; mm < 16; mm <<= 1) {
                s += __shfl_xor(s, mm);
                q += __shfl_xor(q, mm);
            }
            if (m == 0) {
                RED[w * 8 + q4 * 4 + r] = s;
                RED[64 + w * 8 + q4 * 4 + r] = q;
            }
        }
    }
    {
        int rows3 = last ? 64 : 128;
        for (int idx = tid; idx < rows3 * 16; idx += 512) {
            int r = idx >> 4, c = (idx & 15) * 8;
            *(float4*)&Wt[r * 136 + c] = *(const float4*)&w3t[r * HIDD + c];
        }
    }
    __syncthreads();
    if (tid < 8) {
        float s = 0.0f, q = 0.0f;
#pragma unroll
        for (int ww = 0; ww < 8; ++ww) {
            s += RED[ww * 8 + tid];
            q += RED[64 + ww * 8 + tid];
        }
        float mu = s * (1.0f / 128.0f);
        float var = q * (1.0f / 128.0f) - mu * mu;
        RED[128 + tid] = mu;
        RED[136 + tid] = rsqrtf(var + 1e-5f);
    }
    __syncthreads();
    if (q4 < 2) {
        float gv = g[col], bbv = bb[col];
#pragma unroll
        for (int r = 0; r < 4; ++r) {
            int row = q4 * 4 + r;
            float mu = RED[128 + row], rs = RED[136 + row];
            float o = (v[r] - mu) * rs * gv + bbv;
            if (!last) h[(size_t)(r0 + row) * HIDD + col] = o;
            Ab[row * 136 + col] = f2bf(last ? silu_f(o) : o);
        }
    }
    __syncthreads();

    // --- GEMM3: next x  OR  readout ------------------------------------------
    if (!last) {
        f32x4 ac3 = {0, 0, 0, 0};
#pragma unroll
        for (int kc = 0; kc < 128; kc += 32) {
            short8x av = *(const short8x*)&Ab[m * 136 + kc + q8];
            short8x bv = *(const short8x*)&Wt[(w * 16 + m) * 136 + kc + q8];
            ac3 = __builtin_amdgcn_mfma_f32_16x16x32_bf16(av, bv, ac3, 0, 0, 0);
        }
        if (q4 < 2) {
#pragma unroll
            for (int r = 0; r < 4; ++r) {
                int row = q4 * 4 + r;
                xout[(size_t)(r0 + row) * HIDD + col] = f2bf(ac3[r]);
            }
        }
    } else {
        float tsum = 0.0f;
        if (w < 4) {
            f32x4 ac3 = {0, 0, 0, 0};
#pragma unroll
            for (int kc = 0; kc < 128; kc += 32) {
                short8x av = *(const short8x*)&Ab[m * 136 + kc + q8];
                short8x bv = *(const short8x*)&Wt[(w * 16 + m) * 136 + kc + q8];
                ac3 = __builtin_amdgcn_mfma_f32_16x16x32_bf16(av, bv, ac3, 0, 0, 0);
            }
            if (q4 < 2) {
                float bv = rb1[col], wv = rw2[col];
#pragma unroll
                for (int r = 0; r < 4; ++r) tsum += silu_f(ac3[r] + bv) * wv;
            }
#pragma unroll
            for (int mm = 1; mm < 64; mm <<= 1) tsum += __shfl_xor(tsum, mm);
            if (l == 0) RED[144 + w] = tsum;
        }
        __syncthreads();
        if (tid == 0) {
            float tot = RED[144] + RED[145] + RED[146] + RED[147] +
                        (float)FR * rb2[0];
            atomicAdd(&out[blockIdx.x >> 4], tot);
        }
    }
}

extern "C" void kernel_launch(void* const* d_in, const int* in_sizes, int n_in,
                              void* d_out, int out_size, void* d_ws, size_t ws_size,
                              hipStream_t stream) {
    const int*   Z   = (const int*)d_in[0];
    const float* pos = (const float*)d_in[1];
    const int*   ei  = (const int*)d_in[2];
    const float* ew  = (const float*)d_in[3];
    const float* ew1 = (const float*)d_in[4];
    const float* eb1 = (const float*)d_in[5];
    const float* ew2 = (const float*)d_in[6];
    const float* eb2 = (const float*)d_in[7];
    const float* liw = (const float*)d_in[8];
    const float* nw1 = (const float*)d_in[9];
    const float* nb1 = (const float*)d_in[10];
    const float* nw2 = (const float*)d_in[11];
    const float* nb2 = (const float*)d_in[12];
    const float* lng = (const float*)d_in[13];
    const float* lnb = (const float*)d_in[14];
    const float* rw1 = (const float*)d_in[15];
    const float* rb1 = (const float*)d_in[16];
    const float* rw2 = (const float*)d_in[17];
    const float* rb2 = (const float*)d_in[18];
    float* out = (float*)d_out;

    float* h      = (float*)d_ws;                            // 4 MB
    u16*   xb0    = (u16*)(h + (size_t)BN * HIDD);           // 2 MB
    u16*   xb1    = xb0 + (size_t)BN * HIDD;                 // 2 MB
    u16*   lutall = xb1 + (size_t)BN * HIDD;                 // 2 MB
    u16*   liwT   = lutall + (size_t)NBLK * TLUT * HIDD;     // 128 KB
    u16*   nw1T   = liwT + (size_t)NBLK * HIDD * HIDD;
    u16*   nw2T   = nw1T + (size_t)NBLK * HIDD * HIDD;
    u16*   ro1T   = nw2T + (size_t)NBLK * HIDD * HIDD;       // 16 KB
    int*   cnt    = (int*)(ro1T + 64 * HIDD);                // 32 KB
    int*   meta   = (int*)(cnt + BN);                        // 4 MB

    (void)hipMemsetAsync(cnt, 0, BN * sizeof(int), stream);
    k_pe<<<1824, 256, 0, stream>>>(ei, pos, liw, nw1, nw2, rw1,
                                   cnt, meta, liwT, nw1T, nw2T, ro1T,
                                   out, out_size);
    k_le<<<768, 256, 0, stream>>>(ew1, eb1, ew2, eb2, lutall,
                                  Z, ew, liwT, h, xb0);

    u16* xbuf[2] = {xb0, xb1};
    for (int i = 0; i < NBLK; ++i) {
        int last = (i == NBLK - 1);
        k_fiter<<<BN / FR, 512, 0, stream>>>(
            cnt, meta, lutall + (size_t)i * TLUT * HIDD, xbuf[i & 1], h,
            nw1T + (size_t)i * HIDD * HIDD, nb1 + i * HIDD,
            nw2T + (size_t)i * HIDD * HIDD, nb2 + i * HIDD,
            lng + i * HIDD, lnb + i * HIDD,
            last ? ro1T : liwT + (size_t)(i + 1) * HIDD * HIDD,
            last ? (u16*)nullptr : xbuf[(i + 1) & 1],
            last, rb1, rw2, rb2, out);
    }
}